// Round 3
// baseline (8757.240 us; speedup 1.0000x reference)
//
#include <hip/hip_runtime.h>
#include <hip/hip_cooperative_groups.h>

namespace cg = cooperative_groups;

#define DIM     128
#define NVARS   12000
#define NNODES  8400
#define NLEAF   3600
#define NROUNDS 12
#define NODE_CAP 96
#define VAR_CAP  96
#define GRID    256
#define TPB     256

#define NRB_V   ((NVARS + 63) / 64)    // 188
#define NRB_N   ((NNODES + 63) / 64)   // 132
#define NRB_L   ((NLEAF + 63) / 64)    // 57

// LDS layout (floats): sIn[64*129] | sOut[64*129] | sB0[32*68] | sB1[32*68]
#define SIN_OFF  0
#define SOUT_OFF (64 * 129)
#define SB0_OFF  (2 * 64 * 129)        // byte offset 66048, 16B aligned
#define SB1_OFF  (SB0_OFF + 32 * 68)
#define LDS_FLOATS (SB1_OFF + 32 * 68)

struct Params {
    float *h, *c, *t1, *gates;
    const int *ncnt, *nidx, *vcnt, *vidx;
    const float *cm_w1, *cm_b1, *cm_w2, *cm_b2, *cm_w3, *cm_b3;
    const float *pm_w1, *pm_b1, *pm_w2, *pm_b2, *pm_w3, *pm_b3;
    const float *vv_w1, *vv_b1, *vv_w2, *vv_b2, *vv_w3, *vv_b3;
    const float *vu_wih, *vu_whh, *vu_bih, *vu_bhh;
    const float *nu_wih, *nu_whh, *nu_bih, *nu_bhh;
    float *out;
};

__device__ __forceinline__ float sigm(float x) { return 1.f / (1.f + expf(-x)); }

// ---- load 64 rows x 128 cols from global into LDS (pad 129), zero-fill OOB
__device__ __forceinline__ void load_rows(float* lds, const float* __restrict__ src,
                                          int R0, int M) {
    for (int idx = threadIdx.x; idx < 64 * 32; idx += TPB) {
        int r = idx >> 5, q = idx & 31;
        float4 v = make_float4(0.f, 0.f, 0.f, 0.f);
        if (R0 + r < M) v = ((const float4*)(src + (size_t)(R0 + r) * DIM))[q];
        float* d = lds + r * 129 + q * 4;
        d[0] = v.x; d[1] = v.y; d[2] = v.z; d[3] = v.w;
    }
}

// ---- store 64 rows from LDS (pad 129) to global, guarded
__device__ __forceinline__ void store_rows(const float* lds, float* __restrict__ dst,
                                           int R0, int M) {
    __syncthreads();   // all writers of lds done
    for (int idx = threadIdx.x; idx < 64 * 32; idx += TPB) {
        int r = idx >> 5, q = idx & 31;
        if (R0 + r < M) {
            const float* s = lds + r * 129 + q * 4;
            ((float4*)(dst + (size_t)(R0 + r) * DIM))[q] =
                make_float4(s[0], s[1], s[2], s[3]);
        }
    }
}

// ---- one 128->128 layer: out_lds = act(in_lds @ W^T + bias), 64 rows
__device__ __forceinline__ void layer128(const float* __restrict__ in, float* __restrict__ out,
                                         const float* __restrict__ W, const float* __restrict__ bias,
                                         bool relu, float* __restrict__ sB) {
    const int tx = threadIdx.x & 15, ty = threadIdx.x >> 4;
    for (int ct = 0; ct < 2; ++ct) {
        float acc[4][4] = {};
        for (int kk = 0; kk < 128; kk += 32) {
            __syncthreads();   // sB reuse + (first iter) in[] ready
            for (int i = 0; i < 8; ++i) {
                int idx = threadIdx.x + i * TPB;   // 0..2047
                int m = idx >> 5, k = idx & 31;
                sB[k * 68 + m] = W[(ct * 64 + m) * 128 + kk + k];
            }
            __syncthreads();
#pragma unroll
            for (int k = 0; k < 32; ++k) {
                float a[4];
#pragma unroll
                for (int i = 0; i < 4; ++i) a[i] = in[(ty * 4 + i) * 129 + kk + k];
                float4 b = *(const float4*)(sB + k * 68 + tx * 4);
#pragma unroll
                for (int i = 0; i < 4; ++i) {
                    acc[i][0] = fmaf(a[i], b.x, acc[i][0]);
                    acc[i][1] = fmaf(a[i], b.y, acc[i][1]);
                    acc[i][2] = fmaf(a[i], b.z, acc[i][2]);
                    acc[i][3] = fmaf(a[i], b.w, acc[i][3]);
                }
            }
        }
#pragma unroll
        for (int i = 0; i < 4; ++i)
#pragma unroll
            for (int j = 0; j < 4; ++j) {
                int row = ty * 4 + i, col = ct * 64 + tx * 4 + j;
                float v = acc[i][j] + bias[col];
                if (relu) v = fmaxf(v, 0.f);
                out[row * 129 + col] = v;
            }
    }
}

// ---- gather 64 rows: sDst[r][:] = sum_children t1[child][:]
__device__ __forceinline__ void gather64(float* sDst, const float* __restrict__ t1,
                                         const int* __restrict__ cnt, const int* __restrict__ idxm,
                                         int cap, int R0, int M) {
    int rr = threadIdx.x >> 2;    // 0..63
    int q  = threadIdx.x & 3;     // quarter of the 128 dims
    float a[32];
#pragma unroll
    for (int u = 0; u < 32; ++u) a[u] = 0.f;
    int row = R0 + rr;
    if (row < M) {
        int n = cnt[row]; if (n > cap) n = cap;
        const int* ir = idxm + (size_t)row * cap;
        for (int j = 0; j < n; ++j) {
            int ch = ir[j];
            const float4* s4 = (const float4*)(t1 + (size_t)ch * DIM) + q * 8;
#pragma unroll
            for (int u = 0; u < 8; ++u) {
                float4 v = s4[u];
                a[u * 4 + 0] += v.x; a[u * 4 + 1] += v.y;
                a[u * 4 + 2] += v.z; a[u * 4 + 3] += v.w;
            }
        }
    }
    float* d = sDst + rr * 129 + q * 32;
#pragma unroll
    for (int u = 0; u < 32; ++u) d[u] = a[u];
}

// ---- fused LSTM for 64 rows: gates = xin@wih^T + hin@whh^T + biases; pointwise -> h,c
__device__ __forceinline__ void lstm_block(const float* __restrict__ xin, const float* __restrict__ hin,
                                           const float* __restrict__ wih, const float* __restrict__ whh,
                                           const float* __restrict__ bih, const float* __restrict__ bhh,
                                           float* __restrict__ gates, float* __restrict__ h,
                                           float* __restrict__ c, int R0, int M,
                                           float* __restrict__ sB0, float* __restrict__ sB1) {
    const int tx = threadIdx.x & 15, ty = threadIdx.x >> 4;
    for (int ct = 0; ct < 8; ++ct) {
        float acc[4][4] = {};
        for (int kk = 0; kk < 128; kk += 32) {
            __syncthreads();
            for (int i = 0; i < 8; ++i) {
                int idx = threadIdx.x + i * TPB;
                int m = idx >> 5, k = idx & 31;
                sB0[k * 68 + m] = wih[(ct * 64 + m) * 128 + kk + k];
                sB1[k * 68 + m] = whh[(ct * 64 + m) * 128 + kk + k];
            }
            __syncthreads();
#pragma unroll
            for (int k = 0; k < 32; ++k) {
                float a[4], a2[4];
#pragma unroll
                for (int i = 0; i < 4; ++i) {
                    a[i]  = xin[(ty * 4 + i) * 129 + kk + k];
                    a2[i] = hin[(ty * 4 + i) * 129 + kk + k];
                }
                float4 b  = *(const float4*)(sB0 + k * 68 + tx * 4);
                float4 b2 = *(const float4*)(sB1 + k * 68 + tx * 4);
#pragma unroll
                for (int i = 0; i < 4; ++i) {
                    acc[i][0] = fmaf(a[i], b.x,  fmaf(a2[i], b2.x, acc[i][0]));
                    acc[i][1] = fmaf(a[i], b.y,  fmaf(a2[i], b2.y, acc[i][1]));
                    acc[i][2] = fmaf(a[i], b.z,  fmaf(a2[i], b2.z, acc[i][2]));
                    acc[i][3] = fmaf(a[i], b.w,  fmaf(a2[i], b2.w, acc[i][3]));
                }
            }
        }
#pragma unroll
        for (int i = 0; i < 4; ++i)
#pragma unroll
            for (int j = 0; j < 4; ++j) {
                int row = ty * 4 + i, col = ct * 64 + tx * 4 + j;
                if (R0 + row < M)
                    gates[(size_t)(R0 + row) * 512 + col] = acc[i][j] + bih[col] + bhh[col];
            }
    }
    __threadfence();
    __syncthreads();
    // pointwise (same CU wrote these gate rows; L2-hot)
    for (int idx = threadIdx.x; idx < 64 * 128; idx += TPB) {
        int r = idx >> 7, d = idx & 127;
        int row = R0 + r;
        if (row < M) {
            const float* gr = gates + (size_t)row * 512;
            float gi = gr[d], gf = gr[128 + d], gg = gr[256 + d], go = gr[384 + d];
            float cv = c[row * DIM + d];
            float c2 = sigm(gf) * cv + sigm(gi) * tanhf(gg);
            float h2 = sigm(go) * tanhf(c2);
            c[row * DIM + d] = c2;
            h[row * DIM + d] = h2;
        }
    }
}

// ---------------------------------------------------------------------------
__global__ void __launch_bounds__(TPB, 1) mega(Params p) {
    cg::grid_group grid = cg::this_grid();
    __shared__ __align__(16) float lds[LDS_FLOATS];
    float* sIn  = lds + SIN_OFF;
    float* sOut = lds + SOUT_OFF;
    float* sB0  = lds + SB0_OFF;
    float* sB1  = lds + SB1_OFF;

    for (int rd = 0; rd < NROUNDS; ++rd) {
        // P1: t1 = mlp_cm(h) over all vars
        for (int rb = blockIdx.x; rb < NRB_V; rb += gridDim.x) {
            int R0 = rb * 64;
            load_rows(sIn, p.h, R0, NVARS);
            layer128(sIn, sOut, p.cm_w1, p.cm_b1, true,  sB0);
            layer128(sOut, sIn, p.cm_w2, p.cm_b2, true,  sB0);
            layer128(sIn, sOut, p.cm_w3, p.cm_b3, false, sB0);
            store_rows(sOut, p.t1, R0, NVARS);
        }
        grid.sync();
        // P2: node rows: gather children + vu LSTM
        for (int rb = blockIdx.x; rb < NRB_N; rb += gridDim.x) {
            int R0 = rb * 64;
            gather64(sIn, p.t1, p.ncnt, p.nidx, NODE_CAP, R0, NNODES);
            load_rows(sOut, p.h, R0, NNODES);
            lstm_block(sIn, sOut, p.vu_wih, p.vu_whh, p.vu_bih, p.vu_bhh,
                       p.gates, p.h, p.c, R0, NNODES, sB0, sB1);
        }
        grid.sync();
        // P3: t1 = mlp_pm(h[:NNODES])
        for (int rb = blockIdx.x; rb < NRB_N; rb += gridDim.x) {
            int R0 = rb * 64;
            load_rows(sIn, p.h, R0, NNODES);
            layer128(sIn, sOut, p.pm_w1, p.pm_b1, true,  sB0);
            layer128(sOut, sIn, p.pm_w2, p.pm_b2, true,  sB0);
            layer128(sIn, sOut, p.pm_w3, p.pm_b3, false, sB0);
            store_rows(sOut, p.t1, R0, NNODES);
        }
        grid.sync();
        // P4: var rows: gather parents + nu LSTM
        for (int rb = blockIdx.x; rb < NRB_V; rb += gridDim.x) {
            int R0 = rb * 64;
            gather64(sIn, p.t1, p.vcnt, p.vidx, VAR_CAP, R0, NVARS);
            load_rows(sOut, p.h, R0, NVARS);
            lstm_block(sIn, sOut, p.nu_wih, p.nu_whh, p.nu_bih, p.nu_bhh,
                       p.gates, p.h, p.c, R0, NVARS, sB0, sB1);
        }
        grid.sync();
    }
    // vote = mlp_vv(h[NNODES:])[:,0]
    for (int rb = blockIdx.x; rb < NRB_L; rb += gridDim.x) {
        int R0 = NNODES + rb * 64;
        load_rows(sIn, p.h, R0, NVARS);
        layer128(sIn, sOut, p.vv_w1, p.vv_b1, true, sB0);
        layer128(sOut, sIn, p.vv_w2, p.vv_b2, true, sB0);
        __syncthreads();
        if (threadIdx.x < 64) {
            int row = R0 + threadIdx.x;
            if (row < NVARS) {
                float s = p.vv_b3[0];
                for (int k = 0; k < 128; ++k)
                    s = fmaf(sIn[threadIdx.x * 129 + k], p.vv_w3[k], s);
                p.out[row - NNODES] = s;
            }
        }
        __syncthreads();   // protect sIn before next rb's load
    }
}

// ---------------------------------------------------------------------------
__global__ void build_csr(const unsigned int* __restrict__ up,   // fp32 bits
                          int* __restrict__ ncnt, int* __restrict__ nidx,
                          int* __restrict__ vcnt, int* __restrict__ vidx) {
    const int total4 = NNODES * (NVARS / 4);
    const uint4* up4 = (const uint4*)up;
    for (int pidx = blockIdx.x * blockDim.x + threadIdx.x;
         pidx < total4; pidx += gridDim.x * blockDim.x) {
        uint4 w = up4[pidx];
        if ((w.x | w.y | w.z | w.w) == 0u) continue;
        int n  = pidx / (NVARS / 4);
        int v0 = (pidx % (NVARS / 4)) * 4;
        unsigned e[4] = { w.x, w.y, w.z, w.w };
#pragma unroll
        for (int j = 0; j < 4; ++j) {
            if (e[j]) {
                int v = v0 + j;
                int s1 = atomicAdd(&ncnt[n], 1);
                if (s1 < NODE_CAP) nidx[n * NODE_CAP + s1] = v;
                int s2 = atomicAdd(&vcnt[v], 1);
                if (s2 < VAR_CAP) vidx[v * VAR_CAP + s2] = n;
            }
        }
    }
}

__global__ void init_hc(const int* __restrict__ vt,
                        const float* __restrict__ tw, const float* __restrict__ tb,
                        const float* __restrict__ fw, const float* __restrict__ fb,
                        float* __restrict__ h, float* __restrict__ c) {
    int t = blockIdx.x * blockDim.x + threadIdx.x;
    if (t >= NVARS * DIM) return;
    int v = t >> 7, d = t & 127;
    h[t] = (vt[v] == 1) ? (tw[d] + tb[d]) : (fw[d] + fb[d]);
    c[t] = 0.f;
}

// ---------------------------------------------------------------------------
extern "C" void kernel_launch(void* const* d_in, const int* in_sizes, int n_in,
                              void* d_out, int out_size, void* d_ws, size_t ws_size,
                              hipStream_t stream) {
    const int* vt              = (const int*)d_in[0];
    const unsigned int* unpack = (const unsigned int*)d_in[1];
    const float* true_w  = (const float*)d_in[2];
    const float* true_b  = (const float*)d_in[3];
    const float* false_w = (const float*)d_in[4];
    const float* false_b = (const float*)d_in[5];

    Params p;
    p.cm_w1 = (const float*)d_in[6];  p.cm_b1 = (const float*)d_in[7];
    p.cm_w2 = (const float*)d_in[8];  p.cm_b2 = (const float*)d_in[9];
    p.cm_w3 = (const float*)d_in[10]; p.cm_b3 = (const float*)d_in[11];
    p.pm_w1 = (const float*)d_in[12]; p.pm_b1 = (const float*)d_in[13];
    p.pm_w2 = (const float*)d_in[14]; p.pm_b2 = (const float*)d_in[15];
    p.pm_w3 = (const float*)d_in[16]; p.pm_b3 = (const float*)d_in[17];
    p.vv_w1 = (const float*)d_in[18]; p.vv_b1 = (const float*)d_in[19];
    p.vv_w2 = (const float*)d_in[20]; p.vv_b2 = (const float*)d_in[21];
    p.vv_w3 = (const float*)d_in[22]; p.vv_b3 = (const float*)d_in[23];
    p.vu_wih = (const float*)d_in[24]; p.vu_whh = (const float*)d_in[25];
    p.vu_bih = (const float*)d_in[26]; p.vu_bhh = (const float*)d_in[27];
    p.nu_wih = (const float*)d_in[28]; p.nu_whh = (const float*)d_in[29];
    p.nu_bih = (const float*)d_in[30]; p.nu_bhh = (const float*)d_in[31];

    // workspace
    float* h     = (float*)d_ws;
    float* c     = h + NVARS * DIM;
    float* t1    = c + NVARS * DIM;
    float* gates = t1 + NVARS * DIM;
    int* ncnt = (int*)(gates + (size_t)NVARS * 512);
    int* nidx = ncnt + NNODES;
    int* vcnt = nidx + NNODES * NODE_CAP;
    int* vidx = vcnt + NVARS;
    p.h = h; p.c = c; p.t1 = t1; p.gates = gates;
    p.ncnt = ncnt; p.nidx = nidx; p.vcnt = vcnt; p.vidx = vidx;
    p.out = (float*)d_out;

    hipMemsetAsync(ncnt, 0, NNODES * sizeof(int), stream);
    hipMemsetAsync(vcnt, 0, NVARS * sizeof(int), stream);
    build_csr<<<4096, 256, 0, stream>>>(unpack, ncnt, nidx, vcnt, vidx);
    init_hc<<<(NVARS * DIM + 255) / 256, 256, 0, stream>>>(vt, true_w, true_b, false_w, false_b, h, c);

    void* args[] = { &p };
    hipLaunchCooperativeKernel((void*)mega, dim3(GRID), dim3(TPB), args, 0, stream);
}

// Round 6
// 6409.519 us; speedup vs baseline: 1.3663x; 1.3663x over previous
//
#include <hip/hip_runtime.h>

#define NVARS    12000
#define NNODES   8400
#define NLEAF    3600
#define NROUNDS  12
#define NCAP     64
#define VCAP     64
#define GRID     256
#define TPB      256

typedef _Float16 f16;
typedef _Float16 half8 __attribute__((ext_vector_type(8)));
typedef _Float16 half4v __attribute__((ext_vector_type(4)));
typedef float f32x4 __attribute__((ext_vector_type(4)));

#define MROW 136                 // MLP LDS row stride (halves), 272B: 16B-aligned
#define LROW 264                 // LSTM LDS row stride (halves), 528B
#define MLP_LO   (16 * MROW)     // lo-plane offset for MLP tile
#define LSTM_LO  (64 * LROW)     // lo-plane offset for LSTM tile
#define SMEM_HALVES (2 * 64 * LROW)   // 33792 halves = 67.6 KB

struct Params {
    float *h, *c, *t1, *msg, *gates;
    int *bar;                          // software grid barrier counter (zeroed per call)
    const int *ncnt, *nidx, *vcnt, *vidx;
    const f16 *wm_hi, *wm_lo;          // 8 MLP mats, each 16384, [n][k], K=128
    const f16 *vu_hi, *vu_lo;          // [512][256] (k<128: wih, k>=128: whh)
    const f16 *nu_hi, *nu_lo;
    const float *cm_b1, *cm_b2, *cm_b3, *pm_b1, *pm_b2, *pm_b3;
    const float *vv_b1, *vv_b2, *vv_w3, *vv_b3;
    const float *vu_bih, *vu_bhh, *nu_bih, *nu_bhh;
    float *out;
};

__device__ __forceinline__ float sigm(float x) { return 1.f / (1.f + expf(-x)); }

__device__ __forceinline__ f16 hi16(float x) { return (f16)x; }
__device__ __forceinline__ f16 lo16(float x, f16 h) { return (f16)(x - (float)h); }

// ---- software grid barrier: plain launch, all 256 blocks co-resident
// (67.6 KB LDS -> >=1 block/CU, grid == CU count -> capacity >= grid, no deadlock)
__device__ __forceinline__ void gsync(int* bar, int target) {
    __syncthreads();
    __threadfence();                       // release: drain stores device-wide
    if (threadIdx.x == 0) {
        atomicAdd(bar, 1);                 // device-scope, L2-coherent
        while (atomicAdd(bar, 0) < target) // device-scope read
            __builtin_amdgcn_s_sleep(1);
    }
    __syncthreads();
    __threadfence();                       // acquire: invalidate stale L1 lines
}

// D += A*B in near-fp32: (Ah+Al)*(Bh+Bl) minus the negligible Al*Bl term.
__device__ __forceinline__ f32x4 mfma3(half8 ah, half8 al, half8 bh, half8 bl, f32x4 acc) {
    acc = __builtin_amdgcn_mfma_f32_16x16x32_f16(ah, bh, acc, 0, 0, 0);
    acc = __builtin_amdgcn_mfma_f32_16x16x32_f16(al, bh, acc, 0, 0, 0);
    acc = __builtin_amdgcn_mfma_f32_16x16x32_f16(ah, bl, acc, 0, 0, 0);
    return acc;
}

// ---- stage 16 rows x 128 cols fp32 global -> LDS hi/lo fp16 planes
__device__ __forceinline__ void stage16(f16* sHi, f16* sLo, const float* src, int R0) {
#pragma unroll
    for (int i = 0; i < 2; ++i) {
        int fidx = threadIdx.x + i * TPB;        // 0..511
        int r = fidx >> 5, q = fidx & 31;
        float4 v = ((const float4*)(src + (size_t)(R0 + r) * 128))[q];
        half4v hh, ll;
        f16 t0 = hi16(v.x); hh.x = t0; ll.x = lo16(v.x, t0);
        f16 t1 = hi16(v.y); hh.y = t1; ll.y = lo16(v.y, t1);
        f16 t2 = hi16(v.z); hh.z = t2; ll.z = lo16(v.z, t2);
        f16 t3 = hi16(v.w); hh.w = t3; ll.w = lo16(v.w, t3);
        *(half4v*)(sHi + r * MROW + q * 4) = hh;
        *(half4v*)(sLo + r * MROW + q * 4) = ll;
    }
}

// ---- stage 16 rows with fused LSTM pointwise: h,c <- lstm(gates, c); LDS <- h_new
__device__ __forceinline__ void stage16_pw(f16* sHi, f16* sLo, float* h, float* c,
                                           const float* gates, int R0) {
#pragma unroll
    for (int i = 0; i < 8; ++i) {
        int e = threadIdx.x + i * TPB;           // 0..2047
        int r = e >> 7, d = e & 127;
        size_t row = (size_t)(R0 + r);
        const float* gr = gates + row * 512;
        float gi = gr[d], gf = gr[128 + d], gg = gr[256 + d], go = gr[384 + d];
        float cv = c[row * 128 + d];
        float c2 = sigm(gf) * cv + sigm(gi) * tanhf(gg);
        float h2 = sigm(go) * tanhf(c2);
        c[row * 128 + d] = c2;
        h[row * 128 + d] = h2;
        f16 hh = hi16(h2);
        sHi[r * MROW + d] = hh;
        sLo[r * MROW + d] = lo16(h2, hh);
    }
}

// ---- per-wave resident weight fragments for a K=128 layer (32 cols/wave)
struct BFrag { half8 h[2][4]; half8 l[2][4]; };

__device__ __forceinline__ void load_bfrag128(BFrag& B, const f16* Wh, const f16* Wl, int n0) {
    int lane = threadIdx.x & 63, l15 = lane & 15, quad = lane >> 4;
#pragma unroll
    for (int ct = 0; ct < 2; ++ct)
#pragma unroll
        for (int s = 0; s < 4; ++s) {
            size_t off = (size_t)(n0 + ct * 16 + l15) * 128 + s * 32 + quad * 8;
            B.h[ct][s] = *(const half8*)(Wh + off);
            B.l[ct][s] = *(const half8*)(Wl + off);
        }
}

// ---- 16 rows x 128 cols layer GEMM; wave w covers cols [32w, 32w+32)
__device__ __forceinline__ void gemm16(const f16* sHi, const f16* sLo, const BFrag& B,
                                       const float* bias, bool relu, float* dst, int R0) {
    int lane = threadIdx.x & 63, l15 = lane & 15, quad = lane >> 4;
    int w = threadIdx.x >> 6;
    half8 Ah[4], Al[4];
#pragma unroll
    for (int s = 0; s < 4; ++s) {
        int off = l15 * MROW + s * 32 + quad * 8;
        Ah[s] = *(const half8*)(sHi + off);
        Al[s] = *(const half8*)(sLo + off);
    }
    f32x4 acc0 = {0.f, 0.f, 0.f, 0.f}, acc1 = {0.f, 0.f, 0.f, 0.f};
#pragma unroll
    for (int s = 0; s < 4; ++s) {
        acc0 = mfma3(Ah[s], Al[s], B.h[0][s], B.l[0][s], acc0);
        acc1 = mfma3(Ah[s], Al[s], B.h[1][s], B.l[1][s], acc1);
    }
#pragma unroll
    for (int ct = 0; ct < 2; ++ct) {
        int col = w * 32 + ct * 16 + l15;
        float b = bias[col];
        f32x4 a = ct ? acc1 : acc0;
#pragma unroll
        for (int reg = 0; reg < 4; ++reg) {
            int row = quad * 4 + reg;
            float v = a[reg] + b;
            if (relu) v = fmaxf(v, 0.f);
            dst[(size_t)(R0 + row) * 128 + col] = v;
        }
    }
}

// ---- one MLP layer pass over nrows (multiple of 16) rows starting at rbase
__device__ void mlp_pass(f16* sHi, f16* sLo, const float* src, float* dst,
                         const f16* Wh, const f16* Wl, const float* bias, bool relu,
                         int rbase, int nrows, bool pw, float* h, float* c, const float* gates) {
    BFrag B;
    load_bfrag128(B, Wh, Wl, (threadIdx.x >> 6) * 32);
    int nt = nrows >> 4;
    for (int t = blockIdx.x; t < nt; t += GRID) {
        int R0 = rbase + t * 16;
        if (pw) stage16_pw(sHi, sLo, h, c, gates, R0);
        else    stage16(sHi, sLo, src, R0);
        __syncthreads();
        gemm16(sHi, sLo, B, bias, relu, dst, R0);
        __syncthreads();
    }
}

// ---- sparse incidence gather: msg[r] = sum_children t1[child], 8-row tiles
__device__ void gather_phase(const float* t1, float* msg, const int* cnt, const int* idxm,
                             int cap, int nrows) {
    int nt = nrows >> 3;
    int r = threadIdx.x >> 5, g = threadIdx.x & 31;
    for (int t = blockIdx.x; t < nt; t += GRID) {
        int row = t * 8 + r;
        int n = cnt[row]; if (n > cap) n = cap;
        const int* ir = idxm + (size_t)row * cap;
        float4 a = {0.f, 0.f, 0.f, 0.f};
        for (int j = 0; j < n; ++j) {
            float4 v = ((const float4*)(t1 + (size_t)ir[j] * 128))[g];
            a.x += v.x; a.y += v.y; a.z += v.z; a.w += v.w;
        }
        ((float4*)(msg + (size_t)row * 128))[g] = a;
    }
}

// ---- stage 64 rows x K=256 ([msg ; h]) fp32 -> LDS hi/lo fp16
__device__ __forceinline__ void stage64(f16* sHi, f16* sLo, const float* msg, const float* h,
                                        int R0, int rows) {
#pragma unroll
    for (int i = 0; i < 16; ++i) {
        int fidx = threadIdx.x + i * TPB;        // 0..4095
        int r = fidx >> 6, q = fidx & 63;
        float4 v = {0.f, 0.f, 0.f, 0.f};
        if (r < rows) {
            const float* src = (q < 32) ? msg : h;
            v = ((const float4*)(src + (size_t)(R0 + r) * 128))[q & 31];
        }
        half4v hh, ll;
        f16 t0 = hi16(v.x); hh.x = t0; ll.x = lo16(v.x, t0);
        f16 t1 = hi16(v.y); hh.y = t1; ll.y = lo16(v.y, t1);
        f16 t2 = hi16(v.z); hh.z = t2; ll.z = lo16(v.z, t2);
        f16 t3 = hi16(v.w); hh.w = t3; ll.w = lo16(v.w, t3);
        *(half4v*)(sHi + r * LROW + q * 4) = hh;
        *(half4v*)(sLo + r * LROW + q * 4) = ll;
    }
}

// ---- LSTM gates GEMM: gates[r][512] = [msg;h] @ Wcat^T + bih + bhh
__device__ void gates_phase(f16* sHi, f16* sLo, const float* msg, const float* h,
                            const f16* Wh, const f16* Wl, const float* bih, const float* bhh,
                            float* gates, int nrows) {
    int lane = threadIdx.x & 63, l15 = lane & 15, quad = lane >> 4;
    int n0 = (blockIdx.x & 3) * 128 + (threadIdx.x >> 6) * 32;
    half8 Bh[2][8], Bl[2][8];
#pragma unroll
    for (int ct = 0; ct < 2; ++ct)
#pragma unroll
        for (int s = 0; s < 8; ++s) {
            size_t off = (size_t)(n0 + ct * 16 + l15) * 256 + s * 32 + quad * 8;
            Bh[ct][s] = *(const half8*)(Wh + off);
            Bl[ct][s] = *(const half8*)(Wl + off);
        }
    int nrt = (nrows + 63) >> 6;
    for (int rt = (blockIdx.x >> 2); rt < nrt; rt += (GRID / 4)) {
        int R0 = rt * 64;
        int rows = nrows - R0; if (rows > 64) rows = 64;
        stage64(sHi, sLo, msg, h, R0, rows);
        __syncthreads();
        f32x4 acc[4][2];
#pragma unroll
        for (int ms = 0; ms < 4; ++ms) {
            acc[ms][0] = (f32x4){0.f, 0.f, 0.f, 0.f};
            acc[ms][1] = (f32x4){0.f, 0.f, 0.f, 0.f};
        }
#pragma unroll
        for (int ms = 0; ms < 4; ++ms)
#pragma unroll
            for (int s = 0; s < 8; ++s) {
                int off = (ms * 16 + l15) * LROW + s * 32 + quad * 8;
                half8 Ah = *(const half8*)(sHi + off);
                half8 Al = *(const half8*)(sLo + off);
                acc[ms][0] = mfma3(Ah, Al, Bh[0][s], Bl[0][s], acc[ms][0]);
                acc[ms][1] = mfma3(Ah, Al, Bh[1][s], Bl[1][s], acc[ms][1]);
            }
#pragma unroll
        for (int ms = 0; ms < 4; ++ms)
#pragma unroll
            for (int ct = 0; ct < 2; ++ct) {
                int col = n0 + ct * 16 + l15;
                float gb = bih[col] + bhh[col];
#pragma unroll
                for (int reg = 0; reg < 4; ++reg) {
                    int row = ms * 16 + quad * 4 + reg;
                    if (row < rows)
                        gates[(size_t)(R0 + row) * 512 + col] = acc[ms][ct][reg] + gb;
                }
            }
        __syncthreads();
    }
}

// ---- final dot with vv_w3 (fp32 VALU, tiny)
__device__ void vote_dot(const float* act, const float* w3, const float* b3, float* out) {
    int r = threadIdx.x >> 4, seg = threadIdx.x & 15;
    for (int t = blockIdx.x; t < (NLEAF >> 4); t += GRID) {
        const float* row = act + (size_t)(NNODES + t * 16 + r) * 128 + seg * 8;
        float s = 0.f;
#pragma unroll
        for (int u = 0; u < 8; ++u) s += row[u] * w3[seg * 8 + u];
        s += __shfl_xor(s, 1); s += __shfl_xor(s, 2);
        s += __shfl_xor(s, 4); s += __shfl_xor(s, 8);
        if (seg == 0) out[t * 16 + r] = s + b3[0];
    }
}

// ---------------------------------------------------------------------------
__global__ void __launch_bounds__(TPB, 1) mega(Params p) {
    __shared__ __align__(16) f16 sm[SMEM_HALVES];
    f16 *mHi = sm, *mLo = sm + MLP_LO;
    f16 *lHi = sm, *lLo = sm + LSTM_LO;
    int ep = 0;

    for (int rd = 0; rd < NROUNDS; ++rd) {
        // S1: [nu-pointwise if rd>0] + cm-MLP over all vars -> t1
        mlp_pass(mHi, mLo, p.h, p.t1, p.wm_hi + 0 * 16384, p.wm_lo + 0 * 16384, p.cm_b1, true,
                 0, NVARS, rd > 0, p.h, p.c, p.gates);
        mlp_pass(mHi, mLo, p.t1, p.msg, p.wm_hi + 1 * 16384, p.wm_lo + 1 * 16384, p.cm_b2, true,
                 0, NVARS, false, p.h, p.c, p.gates);
        mlp_pass(mHi, mLo, p.msg, p.t1, p.wm_hi + 2 * 16384, p.wm_lo + 2 * 16384, p.cm_b3, false,
                 0, NVARS, false, p.h, p.c, p.gates);
        gsync(p.bar, ++ep * GRID);
        gather_phase(p.t1, p.msg, p.ncnt, p.nidx, NCAP, NNODES);
        gsync(p.bar, ++ep * GRID);
        gates_phase(lHi, lLo, p.msg, p.h, p.vu_hi, p.vu_lo, p.vu_bih, p.vu_bhh, p.gates, NNODES);
        gsync(p.bar, ++ep * GRID);
        // S3: vu-pointwise + pm-MLP over node rows -> t1
        mlp_pass(mHi, mLo, p.h, p.t1, p.wm_hi + 3 * 16384, p.wm_lo + 3 * 16384, p.pm_b1, true,
                 0, NNODES, true, p.h, p.c, p.gates);
        mlp_pass(mHi, mLo, p.t1, p.msg, p.wm_hi + 4 * 16384, p.wm_lo + 4 * 16384, p.pm_b2, true,
                 0, NNODES, false, p.h, p.c, p.gates);
        mlp_pass(mHi, mLo, p.msg, p.t1, p.wm_hi + 5 * 16384, p.wm_lo + 5 * 16384, p.pm_b3, false,
                 0, NNODES, false, p.h, p.c, p.gates);
        gsync(p.bar, ++ep * GRID);
        gather_phase(p.t1, p.msg, p.vcnt, p.vidx, VCAP, NVARS);
        gsync(p.bar, ++ep * GRID);
        gates_phase(lHi, lLo, p.msg, p.h, p.nu_hi, p.nu_lo, p.nu_bih, p.nu_bhh, p.gates, NVARS);
        gsync(p.bar, ++ep * GRID);
    }
    // vote: nu-pointwise on leaf rows + vv MLP + dot
    mlp_pass(mHi, mLo, p.h, p.t1, p.wm_hi + 6 * 16384, p.wm_lo + 6 * 16384, p.vv_b1, true,
             NNODES, NLEAF, true, p.h, p.c, p.gates);
    mlp_pass(mHi, mLo, p.t1, p.msg, p.wm_hi + 7 * 16384, p.wm_lo + 7 * 16384, p.vv_b2, true,
             NNODES, NLEAF, false, p.h, p.c, p.gates);
    vote_dot(p.msg, p.vv_w3, p.vv_b3, p.out);
}

// ---------------------------------------------------------------------------
__global__ void build_csr(const unsigned int* __restrict__ up,   // fp32 bits
                          int* __restrict__ ncnt, int* __restrict__ nidx,
                          int* __restrict__ vcnt, int* __restrict__ vidx) {
    const int total4 = NNODES * (NVARS / 4);
    const uint4* up4 = (const uint4*)up;
    for (int pidx = blockIdx.x * blockDim.x + threadIdx.x;
         pidx < total4; pidx += gridDim.x * blockDim.x) {
        uint4 w = up4[pidx];
        if ((w.x | w.y | w.z | w.w) == 0u) continue;
        int n  = pidx / (NVARS / 4);
        int v0 = (pidx % (NVARS / 4)) * 4;
        unsigned e[4] = { w.x, w.y, w.z, w.w };
#pragma unroll
        for (int j = 0; j < 4; ++j) {
            if (e[j]) {
                int v = v0 + j;
                int s1 = atomicAdd(&ncnt[n], 1);
                if (s1 < NCAP) nidx[n * NCAP + s1] = v;
                int s2 = atomicAdd(&vcnt[v], 1);
                if (s2 < VCAP) vidx[v * VCAP + s2] = n;
            }
        }
    }
}

__global__ void init_hc(const int* __restrict__ vt,
                        const float* __restrict__ tw, const float* __restrict__ tb,
                        const float* __restrict__ fw, const float* __restrict__ fb,
                        float* __restrict__ h, float* __restrict__ c) {
    int t = blockIdx.x * blockDim.x + threadIdx.x;
    if (t >= NVARS * 128) return;
    int d = t & 127;
    h[t] = (vt[t >> 7] == 1) ? (tw[d] + tb[d]) : (fw[d] + fb[d]);
    c[t] = 0.f;
}

struct ConvMLP { const float* src[8]; f16 *hi, *lo; };
__global__ void conv_mlp(ConvMLP a) {
    int idx = blockIdx.x * TPB + threadIdx.x;
    if (idx >= 8 * 16384) return;
    float x = a.src[idx >> 14][idx & 16383];
    f16 h = (f16)x;
    a.hi[idx] = h;
    a.lo[idx] = (f16)(x - (float)h);
}

struct ConvLSTM { const float *wih, *whh; f16 *hi, *lo; };
__global__ void conv_lstm(ConvLSTM a) {
    int idx = blockIdx.x * TPB + threadIdx.x;
    if (idx >= 512 * 256) return;
    int n = idx >> 8, k = idx & 255;
    float x = (k < 128) ? a.wih[n * 128 + k] : a.whh[n * 128 + (k - 128)];
    f16 h = (f16)x;
    a.hi[idx] = h;
    a.lo[idx] = (f16)(x - (float)h);
}

// ---------------------------------------------------------------------------
extern "C" void kernel_launch(void* const* d_in, const int* in_sizes, int n_in,
                              void* d_out, int out_size, void* d_ws, size_t ws_size,
                              hipStream_t stream) {
    const int* vt              = (const int*)d_in[0];
    const unsigned int* unpack = (const unsigned int*)d_in[1];
    const float* true_w  = (const float*)d_in[2];
    const float* true_b  = (const float*)d_in[3];
    const float* false_w = (const float*)d_in[4];
    const float* false_b = (const float*)d_in[5];

    Params p;
    p.cm_b1 = (const float*)d_in[7];  p.cm_b2 = (const float*)d_in[9];
    p.cm_b3 = (const float*)d_in[11];
    p.pm_b1 = (const float*)d_in[13]; p.pm_b2 = (const float*)d_in[15];
    p.pm_b3 = (const float*)d_in[17];
    p.vv_b1 = (const float*)d_in[19]; p.vv_b2 = (const float*)d_in[21];
    p.vv_w3 = (const float*)d_in[22]; p.vv_b3 = (const float*)d_in[23];
    p.vu_bih = (const float*)d_in[26]; p.vu_bhh = (const float*)d_in[27];
    p.nu_bih = (const float*)d_in[30]; p.nu_bhh = (const float*)d_in[31];

    // workspace layout
    float* h     = (float*)d_ws;                 // [NVARS,128]
    float* c     = h + 1536000;
    float* t1    = c + 1536000;
    float* msg   = t1 + 1536000;
    float* gates = msg + 1536000;                // [NVARS,512]
    int* ncnt = (int*)(gates + (size_t)NVARS * 512);
    int* nidx = ncnt + NNODES;                   // [NNODES,NCAP]
    int* vcnt = nidx + NNODES * NCAP;
    int* vidx = vcnt + NVARS;                    // [NVARS,VCAP]
    int* bar  = vidx + NVARS * VCAP;             // barrier counter (+pad)
    uintptr_t wb = (uintptr_t)(bar + 16);
    wb = (wb + 15) & ~(uintptr_t)15;
    f16* wbuf = (f16*)wb;
    f16* wm_hi = wbuf;                // 8*16384
    f16* wm_lo = wm_hi + 131072;
    f16* vu_hi = wm_lo + 131072;      // 512*256
    f16* vu_lo = vu_hi + 131072;
    f16* nu_hi = vu_lo + 131072;
    f16* nu_lo = nu_hi + 131072;

    p.h = h; p.c = c; p.t1 = t1; p.msg = msg; p.gates = gates; p.bar = bar;
    p.ncnt = ncnt; p.nidx = nidx; p.vcnt = vcnt; p.vidx = vidx;
    p.wm_hi = wm_hi; p.wm_lo = wm_lo;
    p.vu_hi = vu_hi; p.vu_lo = vu_lo; p.nu_hi = nu_hi; p.nu_lo = nu_lo;
    p.out = (float*)d_out;

    (void)hipMemsetAsync(ncnt, 0, NNODES * sizeof(int), stream);
    (void)hipMemsetAsync(vcnt, 0, NVARS * sizeof(int), stream);
    (void)hipMemsetAsync(bar, 0, 16 * sizeof(int), stream);
    build_csr<<<4096, 256, 0, stream>>>(unpack, ncnt, nidx, vcnt, vidx);
    init_hc<<<(NVARS * 128) / 256, 256, 0, stream>>>(vt, true_w, true_b, false_w, false_b, h, c);

    ConvMLP cm;
    cm.src[0] = (const float*)d_in[6];  cm.src[1] = (const float*)d_in[8];
    cm.src[2] = (const float*)d_in[10]; cm.src[3] = (const float*)d_in[12];
    cm.src[4] = (const float*)d_in[14]; cm.src[5] = (const float*)d_in[16];
    cm.src[6] = (const float*)d_in[18]; cm.src[7] = (const float*)d_in[20];
    cm.hi = wm_hi; cm.lo = wm_lo;
    conv_mlp<<<512, TPB, 0, stream>>>(cm);

    ConvLSTM cv; cv.wih = (const float*)d_in[24]; cv.whh = (const float*)d_in[25];
    cv.hi = vu_hi; cv.lo = vu_lo;
    conv_lstm<<<512, TPB, 0, stream>>>(cv);
    ConvLSTM cn; cn.wih = (const float*)d_in[28]; cn.whh = (const float*)d_in[29];
    cn.hi = nu_hi; cn.lo = nu_lo;
    conv_lstm<<<512, TPB, 0, stream>>>(cn);

    mega<<<GRID, TPB, 0, stream>>>(p);
}

// Round 7
// 3071.195 us; speedup vs baseline: 2.8514x; 2.0870x over previous
//
#include <hip/hip_runtime.h>

#define NVARS    12000
#define NNODES   8400
#define NLEAF    3600
#define NROUNDS  12
#define RPB      48              // rows per block
#define NB       250             // blocks (250*48 = 12000; node boundary = 175*48)
#define NODE_BLKS 175
#define CAP      64              // CSR fan-in cap (mean ~10, P(>64) ~ 0)
#define TPB      256

typedef _Float16 f16;
typedef _Float16 half8 __attribute__((ext_vector_type(8)));
typedef _Float16 half4v __attribute__((ext_vector_type(4)));
typedef float f32x4 __attribute__((ext_vector_type(4)));

#define MROW 136                 // LDS plane row stride in halves (272B, 16B-aligned)
#define PLANE (RPB * MROW)       // 6528 halves per plane

struct Params {
    float *t1a, *t1b;
    int *bar;
    const int *vt, *ncnt, *nidx, *vcnt, *vidx;
    const float *true_w, *true_b, *false_w, *false_b;
    const f16 *wm_hi, *wm_lo;          // 8 MLP mats [n=128][k=128] hi/lo
    const f16 *vu_hi, *vu_lo;          // [512][256] (k<128: wih, k>=128: whh)
    const f16 *nu_hi, *nu_lo;
    const float *cm_b1, *cm_b2, *cm_b3, *pm_b1, *pm_b2, *pm_b3;
    const float *vv_b1, *vv_b2, *vv_w3, *vv_b3;
    const float *vu_bih, *vu_bhh, *nu_bih, *nu_bhh;
    float *out;
};

__device__ __forceinline__ float sigm(float x) { return 1.f / (1.f + expf(-x)); }

// ---- software grid barrier (proven in round 6; 1 block/CU, NB<=256 -> co-resident)
__device__ __forceinline__ void gsync(int* bar, int target) {
    __syncthreads();
    __threadfence();
    if (threadIdx.x == 0) {
        atomicAdd(bar, 1);
        while (atomicAdd(bar, 0) < target) __builtin_amdgcn_s_sleep(1);
    }
    __syncthreads();
    __threadfence();
}

// D += A*B in near-fp32 split precision (drop negligible Al*Bl).
__device__ __forceinline__ f32x4 mfma3(half8 ah, half8 al, half8 bh, half8 bl, f32x4 acc) {
    acc = __builtin_amdgcn_mfma_f32_16x16x32_f16(ah, bh, acc, 0, 0, 0);
    acc = __builtin_amdgcn_mfma_f32_16x16x32_f16(al, bh, acc, 0, 0, 0);
    acc = __builtin_amdgcn_mfma_f32_16x16x32_f16(ah, bl, acc, 0, 0, 0);
    return acc;
}

// ---- one 128->128 MLP layer over the block's 48 rows.
// in/out: LDS hi/lo planes. If gdst != null: write fp32 to gdst rows grow0+row instead.
__device__ void layerM(const f16* inHi, const f16* inLo,
                       const f16* Wh, const f16* Wl, const float* bias, bool relu,
                       f16* outHi, f16* outLo, float* gdst, int grow0) {
    const int lane = threadIdx.x & 63, l15 = lane & 15, quad = lane >> 4;
    const int w = threadIdx.x >> 6;
    half8 Bh[2][4], Bl[2][4];
#pragma unroll
    for (int ct = 0; ct < 2; ++ct)
#pragma unroll
        for (int s = 0; s < 4; ++s) {
            size_t off = (size_t)(w * 32 + ct * 16 + l15) * 128 + s * 32 + quad * 8;
            Bh[ct][s] = *(const half8*)(Wh + off);
            Bl[ct][s] = *(const half8*)(Wl + off);
        }
    float b0 = bias[w * 32 + l15], b1 = bias[w * 32 + 16 + l15];
#pragma unroll
    for (int mt = 0; mt < 3; ++mt) {
        half8 Ah[4], Al[4];
#pragma unroll
        for (int s = 0; s < 4; ++s) {
            int off = (mt * 16 + l15) * MROW + s * 32 + quad * 8;
            Ah[s] = *(const half8*)(inHi + off);
            Al[s] = *(const half8*)(inLo + off);
        }
        f32x4 acc0 = {0.f, 0.f, 0.f, 0.f}, acc1 = {0.f, 0.f, 0.f, 0.f};
#pragma unroll
        for (int s = 0; s < 4; ++s) {
            acc0 = mfma3(Ah[s], Al[s], Bh[0][s], Bl[0][s], acc0);
            acc1 = mfma3(Ah[s], Al[s], Bh[1][s], Bl[1][s], acc1);
        }
#pragma unroll
        for (int ct = 0; ct < 2; ++ct) {
            f32x4 a = ct ? acc1 : acc0;
            float bb = ct ? b1 : b0;
            int col = w * 32 + ct * 16 + l15;
#pragma unroll
            for (int reg = 0; reg < 4; ++reg) {
                int row = mt * 16 + quad * 4 + reg;
                float v = a[reg] + bb;
                if (relu) v = fmaxf(v, 0.f);
                if (gdst) {
                    gdst[(size_t)(grow0 + row) * 128 + col] = v;
                } else {
                    f16 hh = (f16)v;
                    outHi[row * MROW + col] = hh;
                    outLo[row * MROW + col] = (f16)(v - (float)hh);
                }
            }
        }
    }
    __syncthreads();
}

// ---- LSTM over the block's 48 rows: A=[msg;h] (K=256), 512 gate cols.
// Wave w owns cols w*32..w*32+31 within EACH of i,f,g,o -> pointwise is in-register.
__device__ void gatesL(const f16* msgHi, const f16* msgLo, f16* hHi, f16* hLo, float* cF,
                       const f16* Wh, const f16* Wl, const float* bih, const float* bhh) {
    const int lane = threadIdx.x & 63, l15 = lane & 15, quad = lane >> 4;
    const int w = threadIdx.x >> 6;
    float gb[4][2];
#pragma unroll
    for (int g = 0; g < 4; ++g)
#pragma unroll
        for (int c2 = 0; c2 < 2; ++c2) {
            int col = g * 128 + w * 32 + c2 * 16 + l15;
            gb[g][c2] = bih[col] + bhh[col];
        }
    f32x4 acc[3][4][2];
#pragma unroll
    for (int mt = 0; mt < 3; ++mt)
#pragma unroll
        for (int g = 0; g < 4; ++g)
#pragma unroll
            for (int c2 = 0; c2 < 2; ++c2)
                acc[mt][g][c2] = (f32x4){0.f, 0.f, 0.f, 0.f};

    for (int g = 0; g < 4; ++g) {
        half8 Bh[2][8], Bl[2][8];
#pragma unroll
        for (int c2 = 0; c2 < 2; ++c2)
#pragma unroll
            for (int s = 0; s < 8; ++s) {
                size_t off = (size_t)(g * 128 + w * 32 + c2 * 16 + l15) * 256 + s * 32 + quad * 8;
                Bh[c2][s] = *(const half8*)(Wh + off);
                Bl[c2][s] = *(const half8*)(Wl + off);
            }
#pragma unroll
        for (int mt = 0; mt < 3; ++mt) {
            half8 Ah[8], Al[8];
#pragma unroll
            for (int s = 0; s < 4; ++s) {
                int off = (mt * 16 + l15) * MROW + s * 32 + quad * 8;
                Ah[s]     = *(const half8*)(msgHi + off);
                Al[s]     = *(const half8*)(msgLo + off);
                Ah[s + 4] = *(const half8*)(hHi + off);
                Al[s + 4] = *(const half8*)(hLo + off);
            }
#pragma unroll
            for (int c2 = 0; c2 < 2; ++c2)
#pragma unroll
                for (int s = 0; s < 8; ++s)
                    acc[mt][g][c2] = mfma3(Ah[s], Al[s], Bh[c2][s], Bl[c2][s], acc[mt][g][c2]);
        }
    }
    __syncthreads();   // all h-plane A-reads done before pointwise rewrites h
#pragma unroll
    for (int mt = 0; mt < 3; ++mt)
#pragma unroll
        for (int c2 = 0; c2 < 2; ++c2) {
            int col = w * 32 + c2 * 16 + l15;
#pragma unroll
            for (int reg = 0; reg < 4; ++reg) {
                int row = mt * 16 + quad * 4 + reg;
                float gi = acc[mt][0][c2][reg] + gb[0][c2];
                float gf = acc[mt][1][c2][reg] + gb[1][c2];
                float gg = acc[mt][2][c2][reg] + gb[2][c2];
                float go = acc[mt][3][c2][reg] + gb[3][c2];
                float cv = cF[row * 128 + col];
                float cn = sigm(gf) * cv + sigm(gi) * tanhf(gg);
                float hn = sigm(go) * tanhf(cn);
                cF[row * 128 + col] = cn;
                f16 hh = (f16)hn;
                hHi[row * MROW + col] = hh;
                hLo[row * MROW + col] = (f16)(hn - (float)hh);
            }
        }
    __syncthreads();
}

// ---- gather own 48 rows from global t1 into msg planes (hi/lo)
__device__ void gatherP(const float* t1g, const int* cnt, const int* idxm,
                        f16* msgHi, f16* msgLo, int R0) {
    if (threadIdx.x < 192) {
        int r = threadIdx.x >> 2, q = threadIdx.x & 3;
        int row = R0 + r;
        int n = cnt[row]; if (n > CAP) n = CAP;
        const int* ir = idxm + (size_t)row * CAP;
        float a[32];
#pragma unroll
        for (int u = 0; u < 32; ++u) a[u] = 0.f;
        for (int j = 0; j < n; ++j) {
            const float4* s4 = (const float4*)(t1g + (size_t)ir[j] * 128) + q * 8;
#pragma unroll
            for (int u = 0; u < 8; ++u) {
                float4 v = s4[u];
                a[u * 4 + 0] += v.x; a[u * 4 + 1] += v.y;
                a[u * 4 + 2] += v.z; a[u * 4 + 3] += v.w;
            }
        }
#pragma unroll
        for (int u4 = 0; u4 < 8; ++u4) {
            half4v hh, ll;
#pragma unroll
            for (int k = 0; k < 4; ++k) {
                float x = a[u4 * 4 + k];
                f16 h = (f16)x;
                hh[k] = h; ll[k] = (f16)(x - (float)h);
            }
            int off = r * MROW + q * 32 + u4 * 4;
            *(half4v*)(msgHi + off) = hh;
            *(half4v*)(msgLo + off) = ll;
        }
    }
    __syncthreads();
}

// ---------------------------------------------------------------------------
__global__ void __launch_bounds__(TPB, 1) mega(Params p) {
    __shared__ __align__(16) f16 smh[6 * PLANE];
    __shared__ __align__(16) float cF[RPB * 128];
    f16 *hHi = smh,             *hLo = smh + PLANE;
    f16 *aHi = smh + 2 * PLANE, *aLo = smh + 3 * PLANE;
    f16 *bHi = smh + 4 * PLANE, *bLo = smh + 5 * PLANE;

    const int R0 = blockIdx.x * RPB;
    const bool isNode = blockIdx.x < NODE_BLKS;

    // init own rows: h0 = vt ? (tw+tb) : (fw+fb); c0 = 0
#pragma unroll
    for (int i = 0; i < 24; ++i) {
        int e = threadIdx.x + i * TPB;          // 0..6143
        int r = e >> 7, d = e & 127;
        float hv = (p.vt[R0 + r] == 1) ? (p.true_w[d] + p.true_b[d])
                                       : (p.false_w[d] + p.false_b[d]);
        f16 hh = (f16)hv;
        hHi[r * MROW + d] = hh;
        hLo[r * MROW + d] = (f16)(hv - (float)hh);
        cF[r * 128 + d] = 0.f;
    }
    __syncthreads();

    int ep = 0;
    for (int rd = 0; rd < NROUNDS; ++rd) {
        // cm MLP on own rows -> t1a
        layerM(hHi, hLo, p.wm_hi + 0 * 16384, p.wm_lo + 0 * 16384, p.cm_b1, true,  aHi, aLo, nullptr, 0);
        layerM(aHi, aLo, p.wm_hi + 1 * 16384, p.wm_lo + 1 * 16384, p.cm_b2, true,  bHi, bLo, nullptr, 0);
        layerM(bHi, bLo, p.wm_hi + 2 * 16384, p.wm_lo + 2 * 16384, p.cm_b3, false, nullptr, nullptr, p.t1a, R0);
        gsync(p.bar, ++ep * NB);
        if (isNode) {
            gatherP(p.t1a, p.ncnt, p.nidx, aHi, aLo, R0);
            gatesL(aHi, aLo, hHi, hLo, cF, p.vu_hi, p.vu_lo, p.vu_bih, p.vu_bhh);
            // pm MLP on own (node) rows -> t1b
            layerM(hHi, hLo, p.wm_hi + 3 * 16384, p.wm_lo + 3 * 16384, p.pm_b1, true,  aHi, aLo, nullptr, 0);
            layerM(aHi, aLo, p.wm_hi + 4 * 16384, p.wm_lo + 4 * 16384, p.pm_b2, true,  bHi, bLo, nullptr, 0);
            layerM(bHi, bLo, p.wm_hi + 5 * 16384, p.wm_lo + 5 * 16384, p.pm_b3, false, nullptr, nullptr, p.t1b, R0);
        }
        gsync(p.bar, ++ep * NB);
        gatherP(p.t1b, p.vcnt, p.vidx, aHi, aLo, R0);
        gatesL(aHi, aLo, hHi, hLo, cF, p.nu_hi, p.nu_lo, p.nu_bih, p.nu_bhh);
    }

    // vote on leaf blocks
    if (!isNode) {
        layerM(hHi, hLo, p.wm_hi + 6 * 16384, p.wm_lo + 6 * 16384, p.vv_b1, true, aHi, aLo, nullptr, 0);
        layerM(aHi, aLo, p.wm_hi + 7 * 16384, p.wm_lo + 7 * 16384, p.vv_b2, true, bHi, bLo, nullptr, 0);
        if (threadIdx.x < 192) {
            int r = threadIdx.x >> 2, q = threadIdx.x & 3;
            float s = 0.f;
#pragma unroll
            for (int u = 0; u < 32; ++u) {
                int col = q * 32 + u;
                s += ((float)bHi[r * MROW + col] + (float)bLo[r * MROW + col]) * p.vv_w3[col];
            }
            s += __shfl_xor(s, 1);
            s += __shfl_xor(s, 2);
            if (q == 0) p.out[R0 - NNODES + r] = s + p.vv_b3[0];
        }
    }
}

// ---------------------------------------------------------------------------
__global__ void build_csr(const unsigned int* __restrict__ up,   // fp32 bits
                          int* __restrict__ ncnt, int* __restrict__ nidx,
                          int* __restrict__ vcnt, int* __restrict__ vidx) {
    const int total4 = NNODES * (NVARS / 4);
    const uint4* up4 = (const uint4*)up;
    for (int pidx = blockIdx.x * blockDim.x + threadIdx.x;
         pidx < total4; pidx += gridDim.x * blockDim.x) {
        uint4 w = up4[pidx];
        if ((w.x | w.y | w.z | w.w) == 0u) continue;
        int n  = pidx / (NVARS / 4);
        int v0 = (pidx % (NVARS / 4)) * 4;
        unsigned e[4] = { w.x, w.y, w.z, w.w };
#pragma unroll
        for (int j = 0; j < 4; ++j) {
            if (e[j]) {
                int v = v0 + j;
                int s1 = atomicAdd(&ncnt[n], 1);
                if (s1 < CAP) nidx[n * CAP + s1] = v;
                int s2 = atomicAdd(&vcnt[v], 1);
                if (s2 < CAP) vidx[v * CAP + s2] = n;
            }
        }
    }
}

struct ConvMLP { const float* src[8]; f16 *hi, *lo; };
__global__ void conv_mlp(ConvMLP a) {
    int idx = blockIdx.x * TPB + threadIdx.x;
    if (idx >= 8 * 16384) return;
    float x = a.src[idx >> 14][idx & 16383];
    f16 h = (f16)x;
    a.hi[idx] = h;
    a.lo[idx] = (f16)(x - (float)h);
}

struct ConvLSTM { const float *wih, *whh; f16 *hi, *lo; };
__global__ void conv_lstm(ConvLSTM a) {
    int idx = blockIdx.x * TPB + threadIdx.x;
    if (idx >= 512 * 256) return;
    int n = idx >> 8, k = idx & 255;
    float x = (k < 128) ? a.wih[n * 128 + k] : a.whh[n * 128 + (k - 128)];
    f16 h = (f16)x;
    a.hi[idx] = h;
    a.lo[idx] = (f16)(x - (float)h);
}

// ---------------------------------------------------------------------------
extern "C" void kernel_launch(void* const* d_in, const int* in_sizes, int n_in,
                              void* d_out, int out_size, void* d_ws, size_t ws_size,
                              hipStream_t stream) {
    const unsigned int* unpack = (const unsigned int*)d_in[1];

    Params p;
    p.vt      = (const int*)d_in[0];
    p.true_w  = (const float*)d_in[2];
    p.true_b  = (const float*)d_in[3];
    p.false_w = (const float*)d_in[4];
    p.false_b = (const float*)d_in[5];
    p.cm_b1 = (const float*)d_in[7];  p.cm_b2 = (const float*)d_in[9];
    p.cm_b3 = (const float*)d_in[11];
    p.pm_b1 = (const float*)d_in[13]; p.pm_b2 = (const float*)d_in[15];
    p.pm_b3 = (const float*)d_in[17];
    p.vv_b1 = (const float*)d_in[19]; p.vv_b2 = (const float*)d_in[21];
    p.vv_w3 = (const float*)d_in[22]; p.vv_b3 = (const float*)d_in[23];
    p.vu_bih = (const float*)d_in[26]; p.vu_bhh = (const float*)d_in[27];
    p.nu_bih = (const float*)d_in[30]; p.nu_bhh = (const float*)d_in[31];

    // workspace layout
    float* t1a = (float*)d_ws;                   // [12000][128]
    float* t1b = t1a + (size_t)NVARS * 128;      // [12000][128]
    int* ncnt = (int*)(t1b + (size_t)NVARS * 128);
    int* nidx = ncnt + NNODES;                   // [NNODES][CAP]
    int* vcnt = nidx + NNODES * CAP;
    int* vidx = vcnt + NVARS;                    // [NVARS][CAP]
    int* bar  = vidx + NVARS * CAP;
    uintptr_t wb = (uintptr_t)(bar + 16);
    wb = (wb + 15) & ~(uintptr_t)15;
    f16* wm_hi = (f16*)wb;            // 8*16384
    f16* wm_lo = wm_hi + 131072;
    f16* vu_hi = wm_lo + 131072;      // 512*256
    f16* vu_lo = vu_hi + 131072;
    f16* nu_hi = vu_lo + 131072;
    f16* nu_lo = nu_hi + 131072;

    p.t1a = t1a; p.t1b = t1b; p.bar = bar;
    p.ncnt = ncnt; p.nidx = nidx; p.vcnt = vcnt; p.vidx = vidx;
    p.wm_hi = wm_hi; p.wm_lo = wm_lo;
    p.vu_hi = vu_hi; p.vu_lo = vu_lo; p.nu_hi = nu_hi; p.nu_lo = nu_lo;
    p.out = (float*)d_out;

    (void)hipMemsetAsync(ncnt, 0, NNODES * sizeof(int), stream);
    (void)hipMemsetAsync(vcnt, 0, NVARS * sizeof(int), stream);
    (void)hipMemsetAsync(bar, 0, 16 * sizeof(int), stream);
    build_csr<<<4096, TPB, 0, stream>>>(unpack, ncnt, nidx, vcnt, vidx);

    ConvMLP cm;
    cm.src[0] = (const float*)d_in[6];  cm.src[1] = (const float*)d_in[8];
    cm.src[2] = (const float*)d_in[10]; cm.src[3] = (const float*)d_in[12];
    cm.src[4] = (const float*)d_in[14]; cm.src[5] = (const float*)d_in[16];
    cm.src[6] = (const float*)d_in[18]; cm.src[7] = (const float*)d_in[20];
    cm.hi = wm_hi; cm.lo = wm_lo;
    conv_mlp<<<512, TPB, 0, stream>>>(cm);

    ConvLSTM cv; cv.wih = (const float*)d_in[24]; cv.whh = (const float*)d_in[25];
    cv.hi = vu_hi; cv.lo = vu_lo;
    conv_lstm<<<512, TPB, 0, stream>>>(cv);
    ConvLSTM cn; cn.wih = (const float*)d_in[28]; cn.whh = (const float*)d_in[29];
    cn.hi = nu_hi; cn.lo = nu_lo;
    conv_lstm<<<512, TPB, 0, stream>>>(cn);

    mega<<<NB, TPB, 0, stream>>>(p);
}